// Round 1
// 1127.175 us; speedup vs baseline: 1.2845x; 1.2845x over previous
//
#include <hip/hip_runtime.h>
#include <hip/hip_bf16.h>
#include <stdint.h>

typedef __bf16 bf16_t;
typedef __attribute__((ext_vector_type(8))) __bf16 bf16x8;
typedef __attribute__((ext_vector_type(4))) float f32x4;

#define RMS_EPS 1e-6f

// B=8, N=2048, D=1024, C=1024, H=4096; BN = B*N = 16384
#define DIM_D 1024
#define DIM_C 1024
#define DIM_H 4096
#define DIM_BN 16384

// async 16B global->LDS copy; lds_base must be the wave-uniform chunk base,
// HW writes lane l's 16B at lds_base + l*16 (m104/m108 semantics).
__device__ __forceinline__ void async_copy16(const bf16_t* gsrc,
                                             bf16_t* lds_base) {
  __builtin_amdgcn_global_load_lds(
      (const __attribute__((address_space(1))) uint32_t*)gsrc,
      (__attribute__((address_space(3))) uint32_t*)lds_base, 16, 0, 0);
}

// ---------------- rmsnorm + cast to bf16 (D=1024, block=256) ----------------
__global__ __launch_bounds__(256) void rmsnorm_cast_kernel(
    const float* __restrict__ x, const float* __restrict__ g,
    bf16_t* __restrict__ out) {
  const int row = blockIdx.x;
  const float* xr = x + (size_t)row * DIM_D;
  bf16_t* orow = out + (size_t)row * DIM_D;
  const int tid = threadIdx.x;
  float4 v = ((const float4*)xr)[tid];
  float ss = v.x * v.x + v.y * v.y + v.z * v.z + v.w * v.w;
  for (int off = 32; off > 0; off >>= 1) ss += __shfl_down(ss, off);
  __shared__ float wsum[4];
  const int wave = tid >> 6, lane = tid & 63;
  if (lane == 0) wsum[wave] = ss;
  __syncthreads();
  const float tot = wsum[0] + wsum[1] + wsum[2] + wsum[3];
  const float inv = rsqrtf(tot * (1.0f / DIM_D) + RMS_EPS);
  float4 gv = ((const float4*)g)[tid];
  union { bf16_t h[4]; uint2 u; } o;
  o.h[0] = (bf16_t)(v.x * inv * gv.x);
  o.h[1] = (bf16_t)(v.y * inv * gv.y);
  o.h[2] = (bf16_t)(v.z * inv * gv.z);
  o.h[3] = (bf16_t)(v.w * inv * gv.w);
  *(uint2*)&orow[tid * 4] = o.u;
}

// ---------------- transpose fp32 [R,Cc] -> bf16 [Cc,R] ----------------
__global__ void transpose_cast_kernel(const float* __restrict__ in,
                                      bf16_t* __restrict__ out, int R, int Cc) {
  __shared__ float tile[32][33];
  const int bx = blockIdx.x * 32;  // col base
  const int by = blockIdx.y * 32;  // row base
  const int tx = threadIdx.x, ty = threadIdx.y;  // (32,8)
#pragma unroll
  for (int i = 0; i < 32; i += 8)
    tile[ty + i][tx] = in[(size_t)(by + ty + i) * Cc + bx + tx];
  __syncthreads();
#pragma unroll
  for (int i = 0; i < 32; i += 8)
    out[(size_t)(bx + ty + i) * R + by + tx] = (bf16_t)tile[tx][ty + i];
}

// ---------------- RoPE fp32 [rows,D] -> bf16 [rows,D] ----------------
__global__ __launch_bounds__(256) void rope_cast_kernel(
    const float* __restrict__ x, const int* __restrict__ pos,
    bf16_t* __restrict__ out) {
  const int row = blockIdx.x;
  const float p = (float)pos[row];
  const float* xr = x + (size_t)row * DIM_D;
  bf16_t* orow = out + (size_t)row * DIM_D;
  const int tid = threadIdx.x;
  const float lg = 0.0179889035f;  // ln(10000)/512
#pragma unroll
  for (int t = 0; t < 2; t++) {
    const int i = tid + t * 256;  // pair index 0..511
    const float invf = expf(-(float)i * lg);
    const float ang = p * invf;
    float s, c;
    sincosf(ang, &s, &c);
    float2 x12 = ((const float2*)xr)[i];
    union { bf16_t h[2]; uint32_t u; } o;
    o.h[0] = (bf16_t)(x12.x * c - x12.y * s);
    o.h[1] = (bf16_t)(x12.x * s + x12.y * c);
    *(uint32_t*)&orow[2 * i] = o.u;
  }
}

// ---------------- row softmax over C=1024; writes z fp32 + z bf16 ----------------
__global__ __launch_bounds__(256) void softmax_kernel(
    const float* __restrict__ lat, float* __restrict__ z,
    bf16_t* __restrict__ zb) {
  const int row = blockIdx.x;
  const float* xr = lat + (size_t)row * DIM_C;
  const int tid = threadIdx.x;
  float4 v = ((const float4*)xr)[tid];
  float mx = fmaxf(fmaxf(v.x, v.y), fmaxf(v.z, v.w));
  for (int off = 32; off > 0; off >>= 1) mx = fmaxf(mx, __shfl_down(mx, off));
  __shared__ float sm[4];
  __shared__ float ssum[4];
  const int wave = tid >> 6, lane = tid & 63;
  if (lane == 0) sm[wave] = mx;
  __syncthreads();
  mx = fmaxf(fmaxf(sm[0], sm[1]), fmaxf(sm[2], sm[3]));
  float4 e;
  e.x = __expf(v.x - mx);
  e.y = __expf(v.y - mx);
  e.z = __expf(v.z - mx);
  e.w = __expf(v.w - mx);
  float s = e.x + e.y + e.z + e.w;
  for (int off = 32; off > 0; off >>= 1) s += __shfl_down(s, off);
  if (lane == 0) ssum[wave] = s;
  __syncthreads();
  const float inv = 1.0f / (ssum[0] + ssum[1] + ssum[2] + ssum[3]);
  float4 o;
  o.x = e.x * inv; o.y = e.y * inv; o.z = e.z * inv; o.w = e.w * inv;
  ((float4*)(z + (size_t)row * DIM_C))[tid] = o;
  union { bf16_t h[4]; uint2 u; } ob;
  ob.h[0] = (bf16_t)o.x; ob.h[1] = (bf16_t)o.y;
  ob.h[2] = (bf16_t)o.z; ob.h[3] = (bf16_t)o.w;
  *(uint2*)&zb[(size_t)row * DIM_C + tid * 4] = ob.u;
}

// ---------------- small GEMM (kept for k/v): C[M,N] = A[M,K] @ Bt[N,K]^T ------
// MODE 0: Cf = acc ; MODE 1: Cf = acc + auxf[n]
template <int MODE>
__global__ __launch_bounds__(256, 2) void gemm_bt(
    const bf16_t* __restrict__ A, const bf16_t* __restrict__ Bt,
    int M, int N, int K,
    float* __restrict__ Cf, bf16_t* __restrict__ Cb,
    const float* __restrict__ auxf, const bf16_t* __restrict__ auxb,
    const float* __restrict__ sc_ptr, const float* __restrict__ sc2_ptr,
    float* __restrict__ Cf2, float scale) {
  __shared__ __align__(16) bf16_t As[128 * 32];
  __shared__ __align__(16) bf16_t Bs[128 * 32];
  const int tid = threadIdx.x;
  const int lane = tid & 63;
  const int wave = tid >> 6;
  const int wm = (wave >> 1) * 64;
  const int wn = (wave & 1) * 64;
  const int bm0 = blockIdx.y * 128;
  const int bn0 = blockIdx.x * 128;
  const int quad = lane >> 4;
  const int l16 = lane & 15;
  const int srow = lane >> 2;        // row within 16-row chunk
  const int scol = (lane & 3) * 8;   // k-offset (bf16 elems)

  f32x4 acc[4][4];
#pragma unroll
  for (int i = 0; i < 4; i++)
#pragma unroll
    for (int j = 0; j < 4; j++) acc[i][j] = (f32x4){0.f, 0.f, 0.f, 0.f};

  for (int k0 = 0; k0 < K; k0 += 32) {
#pragma unroll
    for (int h = 0; h < 2; h++) {
      const int chunk = h * 4 + wave;
      const int row = chunk * 16 + srow;
      async_copy16(&A[(size_t)(bm0 + row) * K + k0 + scol], &As[chunk * 512]);
      async_copy16(&Bt[(size_t)(bn0 + row) * K + k0 + scol], &Bs[chunk * 512]);
    }
    __syncthreads();
    bf16x8 af[4], bfr[4];
#pragma unroll
    for (int i = 0; i < 4; i++)
      af[i] = *(const bf16x8*)&As[(wm + i * 16 + l16) * 32 + quad * 8];
#pragma unroll
    for (int j = 0; j < 4; j++)
      bfr[j] = *(const bf16x8*)&Bs[(wn + j * 16 + l16) * 32 + quad * 8];
#pragma unroll
    for (int i = 0; i < 4; i++)
#pragma unroll
      for (int j = 0; j < 4; j++)
        acc[i][j] = __builtin_amdgcn_mfma_f32_16x16x32_bf16(af[i], bfr[j],
                                                            acc[i][j], 0, 0, 0);
    __syncthreads();
  }

#pragma unroll
  for (int i = 0; i < 4; i++) {
#pragma unroll
    for (int j = 0; j < 4; j++) {
      const int n = bn0 + wn + j * 16 + l16;
#pragma unroll
      for (int r = 0; r < 4; r++) {
        const int m = bm0 + wm + i * 16 + quad * 4 + r;
        const size_t idx = (size_t)m * N + n;
        const float v = acc[i][j][r];
        if (MODE == 0) Cf[idx] = v;
        else if (MODE == 1) Cf[idx] = v + auxf[n];
      }
    }
  }
}

// ---------------- 256x256 8-phase GEMM (T2+T3+T4+T5), bf16 in fp32 acc -------
// C[M,N] = A[M,K] @ Bt[N,K]^T ; requires M%256==0, N%256==0, K%64==0, K>=128.
// 8 waves (2M x 4N), per-wave 128x64 out, BK=64, 128KiB LDS = 8 half-tile ring
// slots of 16KiB ([128 rows][64 cols] bf16, XOR-swizzled: byte ^= ((row&7)<<4)).
// Staging: global_load_lds writes LDS linearly; the swizzle is applied by
// permuting the per-lane GLOBAL source address (rule #21), reads apply same XOR.
// Pipeline: 7 half-tiles prefetched in prologue; 1 half-tile staged per phase;
// counted s_waitcnt vmcnt(6) once per K-tile (drain 0 only for last 2 tiles).
// MODE 0: Cf=acc              MODE 3: Cb=bf16(acc)
// MODE 4: Cf=rs*auxf[idx]+acc MODE 5: Cb=bf16(silu(auxb[idx])*acc)
// MODE 6: Cf=auxf[idx]+acc    MODE 7: la=acc*scale; Cf=la;
//                                     Cf2=(la+gns*gumbel(auxf[idx]))/tau
template <int MODE>
__global__ __launch_bounds__(512, 2) void gemm256(
    const bf16_t* __restrict__ A, const bf16_t* __restrict__ Bt,
    int M, int N, int K,
    float* __restrict__ Cf, bf16_t* __restrict__ Cb,
    const float* __restrict__ auxf, const bf16_t* __restrict__ auxb,
    const float* __restrict__ sc_ptr, const float* __restrict__ sc2_ptr,
    float* __restrict__ Cf2, float scale) {
  __shared__ __align__(16) bf16_t lds8[8][8192];
  const int tid = threadIdx.x;
  const int lane = tid & 63;
  const int wave = tid >> 6;          // 0..7
  const int wr = wave >> 2;           // 0..1  (M split)
  const int wc = wave & 3;            // 0..3  (N split)
  const int quad = lane >> 4;
  const int l16 = lane & 15;
  const int srow = lane >> 3;                 // 0..7 staging row-in-8
  const int sc16 = (lane & 7) ^ srow;         // pre-swizzled 16B col block

  // XCD-bijective swizzle (nwg % 8 == 0 for all call sites)
  const int nbx = gridDim.x;
  const int nwg = nbx * (int)gridDim.y;
  int bid = (int)blockIdx.y * nbx + (int)blockIdx.x;
  bid = (bid & 7) * (nwg >> 3) + (bid >> 3);
  const int bn0 = (bid % nbx) * 256;
  const int bm0 = (bid / nbx) * 256;

  const int nkt = K >> 6;
  const int xw = (l16 & 7) << 4;  // read-side XOR (row&7 == l16&7 everywhere)

  auto stage_half = [&](const bf16_t* __restrict__ G, int row0, int k0,
                        int slot) {
#pragma unroll
    for (int h2 = 0; h2 < 2; h2++) {
      const int q = wave * 2 + h2;
      async_copy16(&G[(size_t)(row0 + q * 8 + srow) * K + k0 + sc16 * 8],
                   &lds8[slot][q * 512]);
    }
  };
  auto rdA = [&](int slot, int im, int kk) -> bf16x8 {
    const int lb = (im * 32 + wr * 16 + l16) * 128 + kk * 64 + quad * 16;
    return *(const bf16x8*)((const char*)lds8[slot] + (lb ^ xw));
  };
  auto rdB = [&](int slot, int jn, int kk) -> bf16x8 {
    const int lb = (jn * 64 + wc * 16 + l16) * 128 + kk * 64 + quad * 16;
    return *(const bf16x8*)((const char*)lds8[slot] + (lb ^ xw));
  };

  f32x4 acc[8][4];
#pragma unroll
  for (int i = 0; i < 8; i++)
#pragma unroll
    for (int j = 0; j < 4; j++) acc[i][j] = (f32x4){0.f, 0.f, 0.f, 0.f};

  bf16x8 a[4][2], blo[2][2], bhi[2][2];

  // prologue: 7 half-tiles = K-tile0 {A0,B0,A1,B1} + K-tile1 {A0,B0,A1}
  stage_half(A, bm0, 0, 0);
  stage_half(Bt, bn0, 0, 1);
  stage_half(A, bm0 + 128, 0, 2);
  stage_half(Bt, bn0 + 128, 0, 3);
  stage_half(A, bm0, 64, 4);
  stage_half(Bt, bn0, 64, 5);
  stage_half(A, bm0 + 128, 64, 6);
  asm volatile("s_waitcnt vmcnt(6)" ::: "memory");  // K-tile0 fully landed
  asm volatile("s_barrier" ::: "memory");

  for (int t = 0; t < nkt; ++t) {
    const int b4 = (t & 1) << 2;   // this K-tile's slot base
    const int n4 = b4 ^ 4;         // next K-tile's slot base
    const int k2 = (t + 2) * 64;

    // ---- phase 0: (A-lo, B-lo) ; stage B1(t+1)
#pragma unroll
    for (int im = 0; im < 4; im++)
#pragma unroll
      for (int kk = 0; kk < 2; kk++) a[im][kk] = rdA(b4 + 0, im, kk);
#pragma unroll
    for (int jn = 0; jn < 2; jn++)
#pragma unroll
      for (int kk = 0; kk < 2; kk++) blo[jn][kk] = rdB(b4 + 1, jn, kk);
    if (t + 1 < nkt) stage_half(Bt, bn0 + 128, (t + 1) * 64, n4 + 3);
    asm volatile("s_barrier" ::: "memory");
    asm volatile("s_waitcnt lgkmcnt(0)" ::: "memory");
    __builtin_amdgcn_sched_barrier(0);
    __builtin_amdgcn_s_setprio(1);
#pragma unroll
    for (int im = 0; im < 4; im++)
#pragma unroll
      for (int jn = 0; jn < 2; jn++)
#pragma unroll
        for (int kk = 0; kk < 2; kk++)
          acc[im][jn] = __builtin_amdgcn_mfma_f32_16x16x32_bf16(
              a[im][kk], blo[jn][kk], acc[im][jn], 0, 0, 0);
    __builtin_amdgcn_s_setprio(0);
    asm volatile("s_barrier" ::: "memory");

    // ---- phase 1: (A-lo, B-hi) ; stage A0(t+2) over slot read in phase 0
#pragma unroll
    for (int jn = 0; jn < 2; jn++)
#pragma unroll
      for (int kk = 0; kk < 2; kk++) bhi[jn][kk] = rdB(b4 + 3, jn, kk);
    if (t + 2 < nkt) stage_half(A, bm0, k2, b4 + 0);
    asm volatile("s_barrier" ::: "memory");
    asm volatile("s_waitcnt lgkmcnt(0)" ::: "memory");
    __builtin_amdgcn_sched_barrier(0);
    __builtin_amdgcn_s_setprio(1);
#pragma unroll
    for (int im = 0; im < 4; im++)
#pragma unroll
      for (int jn = 0; jn < 2; jn++)
#pragma unroll
        for (int kk = 0; kk < 2; kk++)
          acc[im][2 + jn] = __builtin_amdgcn_mfma_f32_16x16x32_bf16(
              a[im][kk], bhi[jn][kk], acc[im][2 + jn], 0, 0, 0);
    __builtin_amdgcn_s_setprio(0);
    asm volatile("s_barrier" ::: "memory");

    // ---- phase 2: (A-hi, B-lo regs) ; stage B0(t+2)
#pragma unroll
    for (int im = 0; im < 4; im++)
#pragma unroll
      for (int kk = 0; kk < 2; kk++) a[im][kk] = rdA(b4 + 2, im, kk);
    if (t + 2 < nkt) stage_half(Bt, bn0, k2, b4 + 1);
    asm volatile("s_barrier" ::: "memory");
    asm volatile("s_waitcnt lgkmcnt(0)" ::: "memory");
    __builtin_amdgcn_sched_barrier(0);
    __builtin_amdgcn_s_setprio(1);
#pragma unroll
    for (int im = 0; im < 4; im++)
#pragma unroll
      for (int jn = 0; jn < 2; jn++)
#pragma unroll
        for (int kk = 0; kk < 2; kk++)
          acc[4 + im][jn] = __builtin_amdgcn_mfma_f32_16x16x32_bf16(
              a[im][kk], blo[jn][kk], acc[4 + im][jn], 0, 0, 0);
    __builtin_amdgcn_s_setprio(0);
    asm volatile("s_barrier" ::: "memory");

    // ---- phase 3: (A-hi, B-hi regs) ; stage A1(t+2); counted vmcnt for t+1
    if (t + 2 < nkt) stage_half(A, bm0 + 128, k2, b4 + 2);
    if (t + 2 < nkt) asm volatile("s_waitcnt vmcnt(6)" ::: "memory");
    else             asm volatile("s_waitcnt vmcnt(0)" ::: "memory");
    asm volatile("s_barrier" ::: "memory");
    asm volatile("s_waitcnt lgkmcnt(0)" ::: "memory");
    __builtin_amdgcn_sched_barrier(0);
    __builtin_amdgcn_s_setprio(1);
#pragma unroll
    for (int im = 0; im < 4; im++)
#pragma unroll
      for (int jn = 0; jn < 2; jn++)
#pragma unroll
        for (int kk = 0; kk < 2; kk++)
          acc[4 + im][2 + jn] = __builtin_amdgcn_mfma_f32_16x16x32_bf16(
              a[im][kk], bhi[jn][kk], acc[4 + im][2 + jn], 0, 0, 0);
    __builtin_amdgcn_s_setprio(0);
    asm volatile("s_barrier" ::: "memory");
  }

  // ---- epilogue
  float rs = 0.f, inv_tau = 0.f, gns = 0.f;
  if (MODE == 4) rs = sc_ptr[0];
  if (MODE == 7) { gns = sc_ptr[0]; inv_tau = 1.0f / sc2_ptr[0]; }
#pragma unroll
  for (int i = 0; i < 8; i++) {
#pragma unroll
    for (int j = 0; j < 4; j++) {
      const int n = bn0 + j * 64 + wc * 16 + l16;
#pragma unroll
      for (int r = 0; r < 4; r++) {
        const int m = bm0 + i * 32 + wr * 16 + quad * 4 + r;
        const size_t idx = (size_t)m * N + n;
        const float v = acc[i][j][r];
        if (MODE == 0) {
          Cf[idx] = v;
        } else if (MODE == 3) {
          Cb[idx] = (bf16_t)v;
        } else if (MODE == 4) {
          Cf[idx] = rs * auxf[idx] + v;
        } else if (MODE == 5) {
          const float u = (float)auxb[idx];
          const float su = u / (1.0f + __expf(-u));
          Cb[idx] = (bf16_t)(su * v);
        } else if (MODE == 6) {
          Cf[idx] = auxf[idx] + v;
        } else if (MODE == 7) {
          const float la = v * scale;
          Cf[idx] = la;
          const float u = auxf[idx];
          const float gmb = -__logf(-__logf(u + 1e-10f) + 1e-10f);
          Cf2[idx] = (la + gns * gmb) * inv_tau;
        }
      }
    }
  }
}

// ---------------- launch ----------------
extern "C" void kernel_launch(void* const* d_in, const int* in_sizes, int n_in,
                              void* d_out, int out_size, void* d_ws,
                              size_t ws_size, hipStream_t stream) {
  const float* latents  = (const float*)d_in[0];
  const float* codebook = (const float*)d_in[1];
  const float* Wq = (const float*)d_in[2];
  const float* Wk = (const float*)d_in[3];
  const float* Wv = (const float*)d_in[4];
  const float* bv = (const float*)d_in[5];
  const float* Wc = (const float*)d_in[6];
  const float* w1 = (const float*)d_in[7];
  const float* w2 = (const float*)d_in[8];
  const float* w3 = (const float*)d_in[9];
  const float* g_ctx = (const float*)d_in[10];
  const float* g_q = (const float*)d_in[11];
  const float* g_ff = (const float*)d_in[12];
  const float* un = (const float*)d_in[13];
  const int* positions = (const int*)d_in[14];
  const float* tau = (const float*)d_in[15];
  const float* rs = (const float*)d_in[16];
  const float* gns = (const float*)d_in[17];

  float* out = (float*)d_out;
  const size_t OFF_LA  = 16777216;       // B*N*C
  const size_t OFF_LAT = 2 * 16777216ull;
  const size_t OFF_Z   = 3 * 16777216ull;

  // workspace layout (ws is 1 GiB; peak use 336 MiB)
  char* wsb = (char*)d_ws;
  bf16_t* wqT = (bf16_t*)(wsb + (0ull << 20));     // 2MB
  bf16_t* wkT = (bf16_t*)(wsb + (2ull << 20));     // 2MB
  bf16_t* wvT = (bf16_t*)(wsb + (4ull << 20));     // 2MB
  bf16_t* wcT = (bf16_t*)(wsb + (6ull << 20));     // 2MB
  bf16_t* w1T = (bf16_t*)(wsb + (8ull << 20));     // 8MB
  bf16_t* w3T = (bf16_t*)(wsb + (16ull << 20));    // 8MB
  bf16_t* w2T = (bf16_t*)(wsb + (24ull << 20));    // 8MB
  bf16_t* nctx = (bf16_t*)(wsb + (32ull << 20));   // 2MB
  float*  kf  = (float*)(wsb + (34ull << 20));     // 4MB
  float*  vf  = (float*)(wsb + (38ull << 20));     // 4MB
  bf16_t* kR  = (bf16_t*)(wsb + (42ull << 20));    // 2MB
  bf16_t* vT  = (bf16_t*)(wsb + (44ull << 20));    // 2MB
  bf16_t* nq  = (bf16_t*)(wsb + (48ull << 20));    // 32MB (reused: z bf16)
  bf16_t* zb  = nq;
  float*  qf  = (float*)(wsb + (80ull << 20));     // 64MB (reused: attn_out)
  float*  attn_out = qf;
  bf16_t* qR  = (bf16_t*)(wsb + (144ull << 20));   // 32MB (reused: attn bf16)
  bf16_t* attn_b = qR;
  bf16_t* hbuf = (bf16_t*)(wsb + (176ull << 20));  // 32MB
  bf16_t* ug  = (bf16_t*)(wsb + (208ull << 20));   // 128MB (u then silu(u)*g)

  const dim3 tb32(32, 8);

  // weight transposes (fp32 -> bf16 [N,K] layouts)
  transpose_cast_kernel<<<dim3(32, 32), tb32, 0, stream>>>(Wq, wqT, 1024, 1024);
  transpose_cast_kernel<<<dim3(32, 32), tb32, 0, stream>>>(Wk, wkT, 1024, 1024);
  transpose_cast_kernel<<<dim3(32, 32), tb32, 0, stream>>>(Wv, wvT, 1024, 1024);
  transpose_cast_kernel<<<dim3(32, 32), tb32, 0, stream>>>(Wc, wcT, 1024, 1024);
  transpose_cast_kernel<<<dim3(128, 32), tb32, 0, stream>>>(w1, w1T, 1024, 4096);
  transpose_cast_kernel<<<dim3(128, 32), tb32, 0, stream>>>(w3, w3T, 1024, 4096);
  transpose_cast_kernel<<<dim3(32, 128), tb32, 0, stream>>>(w2, w2T, 4096, 1024);

  // rmsnorms
  rmsnorm_cast_kernel<<<DIM_C, 256, 0, stream>>>(codebook, g_ctx, nctx);
  rmsnorm_cast_kernel<<<DIM_BN, 256, 0, stream>>>(latents, g_q, nq);

  // k, v projections (small M -> 128^2 kernel)
  gemm_bt<0><<<dim3(8, 8), 256, 0, stream>>>(nctx, wkT, 1024, 1024, 1024, kf,
                                             nullptr, nullptr, nullptr, nullptr,
                                             nullptr, nullptr, 0.f);
  gemm_bt<1><<<dim3(8, 8), 256, 0, stream>>>(nctx, wvT, 1024, 1024, 1024, vf,
                                             nullptr, bv, nullptr, nullptr,
                                             nullptr, nullptr, 0.f);
  // q projection (big)
  gemm256<0><<<dim3(4, 64), 512, 0, stream>>>(nq, wqT, DIM_BN, 1024, 1024, qf,
                                              nullptr, nullptr, nullptr, nullptr,
                                              nullptr, nullptr, 0.f);

  // rope + casts
  rope_cast_kernel<<<DIM_BN, 256, 0, stream>>>(qf, positions, qR);
  rope_cast_kernel<<<DIM_C, 256, 0, stream>>>(kf, positions, kR);
  transpose_cast_kernel<<<dim3(32, 32), tb32, 0, stream>>>(vf, vT, 1024, 1024);

  // log_alpha (-> d_out) and log_alpha_tau (-> d_out) fused in epilogue
  gemm256<7><<<dim3(4, 64), 512, 0, stream>>>(qR, kR, DIM_BN, DIM_C, 1024,
                                              out + OFF_LA, nullptr, un,
                                              nullptr, gns, tau,
                                              out + OFF_LAT, 0.03125f);
  // softmax -> z fp32 (d_out) + z bf16 (ws)
  softmax_kernel<<<DIM_BN, 256, 0, stream>>>(out + OFF_LAT, out + OFF_Z, zb);

  // attn = z @ v  (bf16 out)
  gemm256<3><<<dim3(4, 64), 512, 0, stream>>>(zb, vT, DIM_BN, 1024, 1024,
                                              nullptr, attn_b, nullptr, nullptr,
                                              nullptr, nullptr, nullptr, 0.f);
  // attn_out = rs*latents + attn @ Wc
  gemm256<4><<<dim3(4, 64), 512, 0, stream>>>(attn_b, wcT, DIM_BN, 1024, 1024,
                                              attn_out, nullptr, latents,
                                              nullptr, rs, nullptr, nullptr, 0.f);
  // h = rmsnorm(attn_out) * g_ff
  rmsnorm_cast_kernel<<<DIM_BN, 256, 0, stream>>>(attn_out, g_ff, hbuf);

  // FFN, un-chunked: u = h@w1 ; ug = silu(u)*(h@w3) ; out = attn_out + ug@w2
  gemm256<3><<<dim3(16, 64), 512, 0, stream>>>(hbuf, w1T, DIM_BN, DIM_H, 1024,
                                               nullptr, ug, nullptr, nullptr,
                                               nullptr, nullptr, nullptr, 0.f);
  gemm256<5><<<dim3(16, 64), 512, 0, stream>>>(hbuf, w3T, DIM_BN, DIM_H, 1024,
                                               nullptr, ug, nullptr, ug,
                                               nullptr, nullptr, nullptr, 0.f);
  gemm256<6><<<dim3(4, 64), 512, 0, stream>>>(ug, w2T, DIM_BN, DIM_D, DIM_H,
                                              out, nullptr, attn_out,
                                              nullptr, nullptr, nullptr,
                                              nullptr, 0.f);
}

// Round 2
// 1104.340 us; speedup vs baseline: 1.3111x; 1.0207x over previous
//
#include <hip/hip_runtime.h>
#include <hip/hip_bf16.h>
#include <stdint.h>

typedef __bf16 bf16_t;
typedef __attribute__((ext_vector_type(8))) __bf16 bf16x8;
typedef __attribute__((ext_vector_type(4))) float f32x4;

#define RMS_EPS 1e-6f

// B=8, N=2048, D=1024, C=1024, H=4096; BN = B*N = 16384
#define DIM_D 1024
#define DIM_C 1024
#define DIM_H 4096
#define DIM_BN 16384

// async 16B global->LDS copy; lds_base must be the wave-uniform chunk base,
// HW writes lane l's 16B at lds_base + l*16 (m104/m108 semantics).
__device__ __forceinline__ void async_copy16(const bf16_t* gsrc,
                                             bf16_t* lds_base) {
  __builtin_amdgcn_global_load_lds(
      (const __attribute__((address_space(1))) uint32_t*)gsrc,
      (__attribute__((address_space(3))) uint32_t*)lds_base, 16, 0, 0);
}

// ---------------- rmsnorm + cast to bf16 (D=1024, block=256) ----------------
__global__ __launch_bounds__(256) void rmsnorm_cast_kernel(
    const float* __restrict__ x, const float* __restrict__ g,
    bf16_t* __restrict__ out) {
  const int row = blockIdx.x;
  const float* xr = x + (size_t)row * DIM_D;
  bf16_t* orow = out + (size_t)row * DIM_D;
  const int tid = threadIdx.x;
  float4 v = ((const float4*)xr)[tid];
  float ss = v.x * v.x + v.y * v.y + v.z * v.z + v.w * v.w;
  for (int off = 32; off > 0; off >>= 1) ss += __shfl_down(ss, off);
  __shared__ float wsum[4];
  const int wave = tid >> 6, lane = tid & 63;
  if (lane == 0) wsum[wave] = ss;
  __syncthreads();
  const float tot = wsum[0] + wsum[1] + wsum[2] + wsum[3];
  const float inv = rsqrtf(tot * (1.0f / DIM_D) + RMS_EPS);
  float4 gv = ((const float4*)g)[tid];
  union { bf16_t h[4]; uint2 u; } o;
  o.h[0] = (bf16_t)(v.x * inv * gv.x);
  o.h[1] = (bf16_t)(v.y * inv * gv.y);
  o.h[2] = (bf16_t)(v.z * inv * gv.z);
  o.h[3] = (bf16_t)(v.w * inv * gv.w);
  *(uint2*)&orow[tid * 4] = o.u;
}

// ---------------- transpose fp32 [R,Cc] -> bf16 [Cc,R] ----------------
__global__ void transpose_cast_kernel(const float* __restrict__ in,
                                      bf16_t* __restrict__ out, int R, int Cc) {
  __shared__ float tile[32][33];
  const int bx = blockIdx.x * 32;  // col base
  const int by = blockIdx.y * 32;  // row base
  const int tx = threadIdx.x, ty = threadIdx.y;  // (32,8)
#pragma unroll
  for (int i = 0; i < 32; i += 8)
    tile[ty + i][tx] = in[(size_t)(by + ty + i) * Cc + bx + tx];
  __syncthreads();
#pragma unroll
  for (int i = 0; i < 32; i += 8)
    out[(size_t)(bx + ty + i) * R + by + tx] = (bf16_t)tile[tx][ty + i];
}

// ---------------- RoPE fp32 [rows,D] -> bf16 [rows,D] ----------------
__global__ __launch_bounds__(256) void rope_cast_kernel(
    const float* __restrict__ x, const int* __restrict__ pos,
    bf16_t* __restrict__ out) {
  const int row = blockIdx.x;
  const float p = (float)pos[row];
  const float* xr = x + (size_t)row * DIM_D;
  bf16_t* orow = out + (size_t)row * DIM_D;
  const int tid = threadIdx.x;
  const float lg = 0.0179889035f;  // ln(10000)/512
#pragma unroll
  for (int t = 0; t < 2; t++) {
    const int i = tid + t * 256;  // pair index 0..511
    const float invf = expf(-(float)i * lg);
    const float ang = p * invf;
    float s, c;
    sincosf(ang, &s, &c);
    float2 x12 = ((const float2*)xr)[i];
    union { bf16_t h[2]; uint32_t u; } o;
    o.h[0] = (bf16_t)(x12.x * c - x12.y * s);
    o.h[1] = (bf16_t)(x12.x * s + x12.y * c);
    *(uint32_t*)&orow[2 * i] = o.u;
  }
}

// ---------------- row softmax over C=1024; writes z fp32 + z bf16 ----------------
__global__ __launch_bounds__(256) void softmax_kernel(
    const float* __restrict__ lat, float* __restrict__ z,
    bf16_t* __restrict__ zb) {
  const int row = blockIdx.x;
  const float* xr = lat + (size_t)row * DIM_C;
  const int tid = threadIdx.x;
  float4 v = ((const float4*)xr)[tid];
  float mx = fmaxf(fmaxf(v.x, v.y), fmaxf(v.z, v.w));
  for (int off = 32; off > 0; off >>= 1) mx = fmaxf(mx, __shfl_down(mx, off));
  __shared__ float sm[4];
  __shared__ float ssum[4];
  const int wave = tid >> 6, lane = tid & 63;
  if (lane == 0) sm[wave] = mx;
  __syncthreads();
  mx = fmaxf(fmaxf(sm[0], sm[1]), fmaxf(sm[2], sm[3]));
  float4 e;
  e.x = __expf(v.x - mx);
  e.y = __expf(v.y - mx);
  e.z = __expf(v.z - mx);
  e.w = __expf(v.w - mx);
  float s = e.x + e.y + e.z + e.w;
  for (int off = 32; off > 0; off >>= 1) s += __shfl_down(s, off);
  if (lane == 0) ssum[wave] = s;
  __syncthreads();
  const float inv = 1.0f / (ssum[0] + ssum[1] + ssum[2] + ssum[3]);
  float4 o;
  o.x = e.x * inv; o.y = e.y * inv; o.z = e.z * inv; o.w = e.w * inv;
  ((float4*)(z + (size_t)row * DIM_C))[tid] = o;
  union { bf16_t h[4]; uint2 u; } ob;
  ob.h[0] = (bf16_t)o.x; ob.h[1] = (bf16_t)o.y;
  ob.h[2] = (bf16_t)o.z; ob.h[3] = (bf16_t)o.w;
  *(uint2*)&zb[(size_t)row * DIM_C + tid * 4] = ob.u;
}

// ---------------- small GEMM (kept for k/v): C[M,N] = A[M,K] @ Bt[N,K]^T ------
// MODE 0: Cf = acc ; MODE 1: Cf = acc + auxf[n]
template <int MODE>
__global__ __launch_bounds__(256, 2) void gemm_bt(
    const bf16_t* __restrict__ A, const bf16_t* __restrict__ Bt,
    int M, int N, int K,
    float* __restrict__ Cf, bf16_t* __restrict__ Cb,
    const float* __restrict__ auxf, const bf16_t* __restrict__ auxb,
    const float* __restrict__ sc_ptr, const float* __restrict__ sc2_ptr,
    float* __restrict__ Cf2, float scale) {
  __shared__ __align__(16) bf16_t As[128 * 32];
  __shared__ __align__(16) bf16_t Bs[128 * 32];
  const int tid = threadIdx.x;
  const int lane = tid & 63;
  const int wave = tid >> 6;
  const int wm = (wave >> 1) * 64;
  const int wn = (wave & 1) * 64;
  const int bm0 = blockIdx.y * 128;
  const int bn0 = blockIdx.x * 128;
  const int quad = lane >> 4;
  const int l16 = lane & 15;
  const int srow = lane >> 2;        // row within 16-row chunk
  const int scol = (lane & 3) * 8;   // k-offset (bf16 elems)

  f32x4 acc[4][4];
#pragma unroll
  for (int i = 0; i < 4; i++)
#pragma unroll
    for (int j = 0; j < 4; j++) acc[i][j] = (f32x4){0.f, 0.f, 0.f, 0.f};

  for (int k0 = 0; k0 < K; k0 += 32) {
#pragma unroll
    for (int h = 0; h < 2; h++) {
      const int chunk = h * 4 + wave;
      const int row = chunk * 16 + srow;
      async_copy16(&A[(size_t)(bm0 + row) * K + k0 + scol], &As[chunk * 512]);
      async_copy16(&Bt[(size_t)(bn0 + row) * K + k0 + scol], &Bs[chunk * 512]);
    }
    __syncthreads();
    bf16x8 af[4], bfr[4];
#pragma unroll
    for (int i = 0; i < 4; i++)
      af[i] = *(const bf16x8*)&As[(wm + i * 16 + l16) * 32 + quad * 8];
#pragma unroll
    for (int j = 0; j < 4; j++)
      bfr[j] = *(const bf16x8*)&Bs[(wn + j * 16 + l16) * 32 + quad * 8];
#pragma unroll
    for (int i = 0; i < 4; i++)
#pragma unroll
      for (int j = 0; j < 4; j++)
        acc[i][j] = __builtin_amdgcn_mfma_f32_16x16x32_bf16(af[i], bfr[j],
                                                            acc[i][j], 0, 0, 0);
    __syncthreads();
  }

#pragma unroll
  for (int i = 0; i < 4; i++) {
#pragma unroll
    for (int j = 0; j < 4; j++) {
      const int n = bn0 + wn + j * 16 + l16;
#pragma unroll
      for (int r = 0; r < 4; r++) {
        const int m = bm0 + wm + i * 16 + quad * 4 + r;
        const size_t idx = (size_t)m * N + n;
        const float v = acc[i][j][r];
        if (MODE == 0) Cf[idx] = v;
        else if (MODE == 1) Cf[idx] = v + auxf[n];
      }
    }
  }
}

// ---------------- 256x256 8-phase GEMM (T2+T3+T4+T5), bf16 in fp32 acc -------
// Same ring/barrier/vmcnt protocol as the previous (passing) version, but:
//  - t-loop unrolled x2 so ring-slot indices are literals -> ds_read offsets
//    fold into immediates (per-lane byte bases precomputed; XOR swizzle only
//    touches byte bits 4-6, so +slot*16384+im*4096 adds never interact with it)
//  - staging uses 4 incrementally-advanced per-stream pointers (+128 B/K-tile)
//  - phases balanced 8/4/8/4: B-lo frags of tile t+1 are prefetched in phase 3
//    of tile t (safe: ph3's vmcnt(6)+barrier guarantee all of t+1 landed; blo
//    regs are dead after ph2's MFMA cluster).
// MODE 0: Cf=acc              MODE 3: Cb=bf16(acc)
// MODE 4: Cf=rs*auxf[idx]+acc MODE 5: Cb=bf16(silu(auxb[idx])*acc)
// MODE 6: Cf=auxf[idx]+acc    MODE 7: la=acc*scale; Cf=la;
//                                     Cf2=(la+gns*gumbel(auxf[idx]))/tau
#define BARRIER asm volatile("s_barrier" ::: "memory")
#define LGKM0   asm volatile("s_waitcnt lgkmcnt(0)" ::: "memory")
#define VMC6    asm volatile("s_waitcnt vmcnt(6)" ::: "memory")
#define VMC0    asm volatile("s_waitcnt vmcnt(0)" ::: "memory")
#define SCHED0  __builtin_amdgcn_sched_barrier(0)

#define RD8A(SLOT)                                                            \
  _Pragma("unroll") for (int im = 0; im < 4; im++) {                          \
    a[im][0] = *(const bf16x8*)(pa0 + ((SLOT)*16384 + im * 4096));            \
    a[im][1] = *(const bf16x8*)(pa1 + ((SLOT)*16384 + im * 4096));            \
  }
#define RD4B(DST, SLOT)                                                       \
  _Pragma("unroll") for (int jn = 0; jn < 2; jn++) {                          \
    DST[jn][0] = *(const bf16x8*)(pb0 + ((SLOT)*16384 + jn * 8192));          \
    DST[jn][1] = *(const bf16x8*)(pb1 + ((SLOT)*16384 + jn * 8192));          \
  }
#define MFMAQ(IOFS, BR, JOFS)                                                 \
  __builtin_amdgcn_s_setprio(1);                                              \
  _Pragma("unroll") for (int im = 0; im < 4; im++)                            \
  _Pragma("unroll") for (int jn = 0; jn < 2; jn++)                            \
  _Pragma("unroll") for (int kk = 0; kk < 2; kk++)                            \
    acc[(IOFS) + im][(JOFS) + jn] = __builtin_amdgcn_mfma_f32_16x16x32_bf16(  \
        a[im][kk], BR[jn][kk], acc[(IOFS) + im][(JOFS) + jn], 0, 0, 0);       \
  __builtin_amdgcn_s_setprio(0);

// One K-tile, 4 phases. B4: slot base literal (0 or 4). S1: stage B1(t+1).
// S2: stage A0/B0/A1(t+2). PREF: prefetch blo(t+1) in ph3. VM6: counted wait.
#define KTILE(B4, S1, S2, PREF, VM6)                                          \
  {                                                                           \
    /* ph0: read A-lo(t); stage B1(t+1) */                                    \
    RD8A((B4) + 0);                                                           \
    if (S1) STAGE2(pBhi, ((B4) ^ 4) + 3);                                     \
    BARRIER; LGKM0; SCHED0;                                                   \
    MFMAQ(0, blo, 0);                                                         \
    BARRIER;                                                                  \
    /* ph1: read B-hi(t); stage A0(t+2) */                                    \
    RD4B(bhi, (B4) + 3);                                                      \
    if (S2) STAGE2(pAlo, (B4) + 0);                                           \
    BARRIER; LGKM0; SCHED0;                                                   \
    MFMAQ(0, bhi, 2);                                                         \
    BARRIER;                                                                  \
    /* ph2: read A-hi(t); stage B0(t+2) */                                    \
    RD8A((B4) + 2);                                                           \
    if (S2) STAGE2(pBlo, (B4) + 1);                                           \
    BARRIER; LGKM0; SCHED0;                                                   \
    MFMAQ(4, blo, 0);                                                         \
    BARRIER;                                                                  \
    /* ph3: stage A1(t+2); counted vmcnt; prefetch blo(t+1) */                \
    if (S2) STAGE2(pAhi, (B4) + 2);                                           \
    if (VM6) { VMC6; } else { VMC0; }                                         \
    BARRIER; LGKM0; SCHED0;                                                   \
    if (PREF) RD4B(blo, ((B4) ^ 4) + 1);                                      \
    MFMAQ(4, bhi, 2);                                                         \
    BARRIER;                                                                  \
  }

template <int MODE>
__global__ __launch_bounds__(512, 2) void gemm256(
    const bf16_t* __restrict__ A, const bf16_t* __restrict__ Bt,
    int M, int N, int K,
    float* __restrict__ Cf, bf16_t* __restrict__ Cb,
    const float* __restrict__ auxf, const bf16_t* __restrict__ auxb,
    const float* __restrict__ sc_ptr, const float* __restrict__ sc2_ptr,
    float* __restrict__ Cf2, float scale) {
  __shared__ __align__(16) bf16_t lds[8 * 8192];  // 8 half-tile slots x 16 KiB
  const int tid = threadIdx.x;
  const int lane = tid & 63;
  const int wave = tid >> 6;          // 0..7
  const int wr = wave >> 2;           // 0..1  (M split)
  const int wc = wave & 3;            // 0..3  (N split)
  const int quad = lane >> 4;
  const int l16 = lane & 15;
  const int srow = lane >> 3;                 // 0..7 staging row-in-8
  const int sc16 = (lane & 7) ^ srow;         // pre-swizzled 16B col block

  // XCD-bijective swizzle (nwg % 8 == 0 for all call sites)
  const int nbx = gridDim.x;
  const int nwg = nbx * (int)gridDim.y;
  int bid = (int)blockIdx.y * nbx + (int)blockIdx.x;
  bid = (bid & 7) * (nwg >> 3) + (bid >> 3);
  const int bn0 = (bid % nbx) * 256;
  const int bm0 = (bid / nbx) * 256;

  const int nkt = K >> 6;

  // ---- per-lane LDS read byte-bases (XOR swizzle folded; bits 4-6 only) ----
  const int xw = (l16 & 7) << 4;
  const char* ldsc = (const char*)lds;
  const char* pa0 = ldsc + (wr * 16 + l16) * 128 + ((quad * 16) ^ xw);
  const char* pa1 = ldsc + (wr * 16 + l16) * 128 + (((64 + quad * 16)) ^ xw);
  const char* pb0 = ldsc + (wc * 16 + l16) * 128 + ((quad * 16) ^ xw);
  const char* pb1 = ldsc + (wc * 16 + l16) * 128 + (((64 + quad * 16)) ^ xw);

  // ---- staging: 4 stream pointers, advanced +128 B per stage event ----
  const size_t kb16 = (size_t)K * 16;  // 8 rows of bf16
  bf16_t* ldsw = lds + wave * 1024;    // elems; +slot*8192, +512 for h2=1
  const char* pAlo = (const char*)A +
      2 * ((size_t)(bm0 + wave * 16 + srow) * K + sc16 * 8);
  const char* pAhi = (const char*)A +
      2 * ((size_t)(bm0 + 128 + wave * 16 + srow) * K + sc16 * 8);
  const char* pBlo = (const char*)Bt +
      2 * ((size_t)(bn0 + wave * 16 + srow) * K + sc16 * 8);
  const char* pBhi = (const char*)Bt +
      2 * ((size_t)(bn0 + 128 + wave * 16 + srow) * K + sc16 * 8);

#define STAGE2(P, SLOT)                                                       \
  {                                                                           \
    async_copy16((const bf16_t*)(P), ldsw + (SLOT)*8192);                     \
    async_copy16((const bf16_t*)((P) + kb16), ldsw + (SLOT)*8192 + 512);      \
    P += 128;                                                                 \
  }

  f32x4 acc[8][4];
#pragma unroll
  for (int i = 0; i < 8; i++)
#pragma unroll
    for (int j = 0; j < 4; j++) acc[i][j] = (f32x4){0.f, 0.f, 0.f, 0.f};

  bf16x8 a[4][2], blo[2][2], bhi[2][2];

  // prologue: 7 half-tiles = K-tile0 {A0,B0,A1,B1} + K-tile1 {A0,B0,A1}
  STAGE2(pAlo, 0);
  STAGE2(pBlo, 1);
  STAGE2(pAhi, 2);
  STAGE2(pBhi, 3);
  STAGE2(pAlo, 4);
  STAGE2(pBlo, 5);
  STAGE2(pAhi, 6);
  VMC6;      // K-tile0 fully landed (own chunks)
  BARRIER;   // -> visible to all waves
  RD4B(blo, 1);  // B-lo(t=0); drained by ph0's LGKM0

  // main loop: full-guard pairs; last pair peeled (nkt even, >=4)
  for (int t = 0; t + 3 < nkt; t += 2) {
    KTILE(0, 1, 1, 1, 1);
    KTILE(4, 1, 1, 1, 1);
  }
  KTILE(0, 1, 0, 1, 0);  // t = nkt-2: stage B1(nkt-1) only; drain all
  KTILE(4, 0, 0, 0, 0);  // t = nkt-1: pure compute

  // ---- epilogue
  float rs = 0.f, inv_tau = 0.f, gns = 0.f;
  if (MODE == 4) rs = sc_ptr[0];
  if (MODE == 7) { gns = sc_ptr[0]; inv_tau = 1.0f / sc2_ptr[0]; }
#pragma unroll
  for (int i = 0; i < 8; i++) {
#pragma unroll
    for (int j = 0; j < 4; j++) {
      const int n = bn0 + j * 64 + wc * 16 + l16;
#pragma unroll
      for (int r = 0; r < 4; r++) {
        const int m = bm0 + i * 32 + wr * 16 + quad * 4 + r;
        const size_t idx = (size_t)m * N + n;
        const float v = acc[i][j][r];
        if (MODE == 0) {
          Cf[idx] = v;
        } else if (MODE == 3) {
          Cb[idx] = (bf16_t)v;
        } else if (MODE == 4) {
          Cf[idx] = rs * auxf[idx] + v;
        } else if (MODE == 5) {
          const float u = (float)auxb[idx];
          const float su = u / (1.0f + __expf(-u));
          Cb[idx] = (bf16_t)(su * v);
        } else if (MODE == 6) {
          Cf[idx] = auxf[idx] + v;
        } else if (MODE == 7) {
          const float la = v * scale;
          Cf[idx] = la;
          const float u = auxf[idx];
          const float gmb = -__logf(-__logf(u + 1e-10f) + 1e-10f);
          Cf2[idx] = (la + gns * gmb) * inv_tau;
        }
      }
    }
  }
}

// ---------------- launch ----------------
extern "C" void kernel_launch(void* const* d_in, const int* in_sizes, int n_in,
                              void* d_out, int out_size, void* d_ws,
                              size_t ws_size, hipStream_t stream) {
  const float* latents  = (const float*)d_in[0];
  const float* codebook = (const float*)d_in[1];
  const float* Wq = (const float*)d_in[2];
  const float* Wk = (const float*)d_in[3];
  const float* Wv = (const float*)d_in[4];
  const float* bv = (const float*)d_in[5];
  const float* Wc = (const float*)d_in[6];
  const float* w1 = (const float*)d_in[7];
  const float* w2 = (const float*)d_in[8];
  const float* w3 = (const float*)d_in[9];
  const float* g_ctx = (const float*)d_in[10];
  const float* g_q = (const float*)d_in[11];
  const float* g_ff = (const float*)d_in[12];
  const float* un = (const float*)d_in[13];
  const int* positions = (const int*)d_in[14];
  const float* tau = (const float*)d_in[15];
  const float* rs = (const float*)d_in[16];
  const float* gns = (const float*)d_in[17];

  float* out = (float*)d_out;
  const size_t OFF_LA  = 16777216;       // B*N*C
  const size_t OFF_LAT = 2 * 16777216ull;
  const size_t OFF_Z   = 3 * 16777216ull;

  // workspace layout (ws is 1 GiB; peak use 336 MiB)
  char* wsb = (char*)d_ws;
  bf16_t* wqT = (bf16_t*)(wsb + (0ull << 20));     // 2MB
  bf16_t* wkT = (bf16_t*)(wsb + (2ull << 20));     // 2MB
  bf16_t* wvT = (bf16_t*)(wsb + (4ull << 20));     // 2MB
  bf16_t* wcT = (bf16_t*)(wsb + (6ull << 20));     // 2MB
  bf16_t* w1T = (bf16_t*)(wsb + (8ull << 20));     // 8MB
  bf16_t* w3T = (bf16_t*)(wsb + (16ull << 20));    // 8MB
  bf16_t* w2T = (bf16_t*)(wsb + (24ull << 20));    // 8MB
  bf16_t* nctx = (bf16_t*)(wsb + (32ull << 20));   // 2MB
  float*  kf  = (float*)(wsb + (34ull << 20));     // 4MB
  float*  vf  = (float*)(wsb + (38ull << 20));     // 4MB
  bf16_t* kR  = (bf16_t*)(wsb + (42ull << 20));    // 2MB
  bf16_t* vT  = (bf16_t*)(wsb + (44ull << 20));    // 2MB
  bf16_t* nq  = (bf16_t*)(wsb + (48ull << 20));    // 32MB (reused: z bf16)
  bf16_t* zb  = nq;
  float*  qf  = (float*)(wsb + (80ull << 20));     // 64MB (reused: attn_out)
  float*  attn_out = qf;
  bf16_t* qR  = (bf16_t*)(wsb + (144ull << 20));   // 32MB (reused: attn bf16)
  bf16_t* attn_b = qR;
  bf16_t* hbuf = (bf16_t*)(wsb + (176ull << 20));  // 32MB
  bf16_t* ug  = (bf16_t*)(wsb + (208ull << 20));   // 128MB (u then silu(u)*g)

  const dim3 tb32(32, 8);

  // weight transposes (fp32 -> bf16 [N,K] layouts)
  transpose_cast_kernel<<<dim3(32, 32), tb32, 0, stream>>>(Wq, wqT, 1024, 1024);
  transpose_cast_kernel<<<dim3(32, 32), tb32, 0, stream>>>(Wk, wkT, 1024, 1024);
  transpose_cast_kernel<<<dim3(32, 32), tb32, 0, stream>>>(Wv, wvT, 1024, 1024);
  transpose_cast_kernel<<<dim3(32, 32), tb32, 0, stream>>>(Wc, wcT, 1024, 1024);
  transpose_cast_kernel<<<dim3(128, 32), tb32, 0, stream>>>(w1, w1T, 1024, 4096);
  transpose_cast_kernel<<<dim3(128, 32), tb32, 0, stream>>>(w3, w3T, 1024, 4096);
  transpose_cast_kernel<<<dim3(32, 128), tb32, 0, stream>>>(w2, w2T, 4096, 1024);

  // rmsnorms
  rmsnorm_cast_kernel<<<DIM_C, 256, 0, stream>>>(codebook, g_ctx, nctx);
  rmsnorm_cast_kernel<<<DIM_BN, 256, 0, stream>>>(latents, g_q, nq);

  // k, v projections (small M -> 128^2 kernel)
  gemm_bt<0><<<dim3(8, 8), 256, 0, stream>>>(nctx, wkT, 1024, 1024, 1024, kf,
                                             nullptr, nullptr, nullptr, nullptr,
                                             nullptr, nullptr, 0.f);
  gemm_bt<1><<<dim3(8, 8), 256, 0, stream>>>(nctx, wvT, 1024, 1024, 1024, vf,
                                             nullptr, bv, nullptr, nullptr,
                                             nullptr, nullptr, 0.f);
  // q projection (big)
  gemm256<0><<<dim3(4, 64), 512, 0, stream>>>(nq, wqT, DIM_BN, 1024, 1024, qf,
                                              nullptr, nullptr, nullptr, nullptr,
                                              nullptr, nullptr, 0.f);

  // rope + casts
  rope_cast_kernel<<<DIM_BN, 256, 0, stream>>>(qf, positions, qR);
  rope_cast_kernel<<<DIM_C, 256, 0, stream>>>(kf, positions, kR);
  transpose_cast_kernel<<<dim3(32, 32), tb32, 0, stream>>>(vf, vT, 1024, 1024);

  // log_alpha (-> d_out) and log_alpha_tau (-> d_out) fused in epilogue
  gemm256<7><<<dim3(4, 64), 512, 0, stream>>>(qR, kR, DIM_BN, DIM_C, 1024,
                                              out + OFF_LA, nullptr, un,
                                              nullptr, gns, tau,
                                              out + OFF_LAT, 0.03125f);
  // softmax -> z fp32 (d_out) + z bf16 (ws)
  softmax_kernel<<<DIM_BN, 256, 0, stream>>>(out + OFF_LAT, out + OFF_Z, zb);

  // attn = z @ v  (bf16 out)
  gemm256<3><<<dim3(4, 64), 512, 0, stream>>>(zb, vT, DIM_BN, 1024, 1024,
                                              nullptr, attn_b, nullptr, nullptr,
                                              nullptr, nullptr, nullptr, 0.f);
  // attn_out = rs*latents + attn @ Wc
  gemm256<4><<<dim3(4, 64), 512, 0, stream>>>(attn_b, wcT, DIM_BN, 1024, 1024,
                                              attn_out, nullptr, latents,
                                              nullptr, rs, nullptr, nullptr, 0.f);
  // h = rmsnorm(attn_out) * g_ff
  rmsnorm_cast_kernel<<<DIM_BN, 256, 0, stream>>>(attn_out, g_ff, hbuf);

  // FFN, un-chunked: u = h@w1 ; ug = silu(u)*(h@w3) ; out = attn_out + ug@w2
  gemm256<3><<<dim3(16, 64), 512, 0, stream>>>(hbuf, w1T, DIM_BN, DIM_H, 1024,
                                               nullptr, ug, nullptr, nullptr,
                                               nullptr, nullptr, nullptr, 0.f);
  gemm256<5><<<dim3(16, 64), 512, 0, stream>>>(hbuf, w3T, DIM_BN, DIM_H, 1024,
                                               nullptr, ug, nullptr, ug,
                                               nullptr, nullptr, nullptr, 0.f);
  gemm256<6><<<dim3(4, 64), 512, 0, stream>>>(ug, w2T, DIM_BN, DIM_D, DIM_H,
                                              out, nullptr, attn_out,
                                              nullptr, nullptr, nullptr,
                                              nullptr, 0.f);
}